// Round 8
// baseline (90.838 us; speedup 1.0000x reference)
//
#include <hip/hip_runtime.h>
#include <stdint.h>

// Problem constants (B,C,H,W)=(4,128,64,128), R=4, D=9, out channels 81.
// out[b, di*9+dj, h, w] = sum_c src[b,c,h,w] * tgt[b,c,h+di-8,w+dj-8]
// (zero when the shifted index leaves [0,H)x[0,W); shifts are [-8,0]).
//
// v9 = v8's converter + v7's block shape (all 9 di per block), minus both
// of their sins. R7 analysis: v8's main kernel (2304 tiny blocks) re-read
// the A panel 9x and paid block setup + 2 barriers per 8-16 MFMAs; v7's
// per-di f32 staging+f2bf was 95% of its time. Here: block=(b,h) (grid
// 256 = 1/CU, XCD-pinned), A fragments loaded once from pre-converted
// d_ws, 9 unrolled di iterations of pure register-loads+MFMA scattering
// into disjoint per-di LDS slices (no intra-loop barriers -> compiler
// pipelines di+1 loads under di MFMA), ONE barrier, one store pass.
#define NB 4
#define NC 128
#define NH 64
#define NW 128
#define HW (NH * NW)      // 8192
#define ND 9
#define NOUT (ND * ND)    // 81
#define PLANE 16384       // halfwords per (b,row) bf16 K-panel plane (32 KB)
#define TGT_OFF ((size_t)NB * NH * PLANE)  // tgt planes after src planes
#define TILE (ND * NW)    // floats per di slice of out-LDS (1152)

typedef __attribute__((ext_vector_type(8))) short short8;
typedef __attribute__((ext_vector_type(4))) float f32x4;

__device__ __forceinline__ ushort f2bf(float f) {  // RNE f32->bf16
  uint u = __float_as_uint(f);
  u += 0x7FFFu + ((u >> 16) & 1u);
  return (ushort)(u >> 16);
}

// ---- pass 1 (unchanged from v8, refcheck'd): f32 -> bf16 K-panel planes.
// plane(b,row)[oct=c>>3][w][c&7]; LDS-transposed so reads and writes are
// both coalesced.
__global__ __launch_bounds__(512, 2) void convert_kernel(const float* __restrict__ src,
                                                         const float* __restrict__ tgt,
                                                         ushort* __restrict__ ws) {
  __shared__ ushort pl[PLANE];
  const int t   = blockIdx.x >> 8;        // 0 = src, 1 = tgt
  const int b   = (blockIdx.x >> 6) & 3;
  const int row = blockIdx.x & 63;
  const float* in = (t ? tgt : src) + (size_t)(b * NC) * HW + row * NW;
  ushort* outp = ws + (t ? TGT_OFF : 0) + (size_t)(b * NH + row) * PLANE;

#pragma unroll
  for (int i = 0; i < 8; ++i) {
    const int cell = i * 512 + threadIdx.x;  // 4096 cells = 32 c-quads x 128 w
    const int c0 = (cell >> 7) << 2;         // 0,4,...,124
    const int w  = cell & 127;
    ushort4 e;
    e.x = f2bf(in[(size_t)(c0 + 0) * HW + w]);
    e.y = f2bf(in[(size_t)(c0 + 1) * HW + w]);
    e.z = f2bf(in[(size_t)(c0 + 2) * HW + w]);
    e.w = f2bf(in[(size_t)(c0 + 3) * HW + w]);
    *(ushort4*)&pl[(c0 >> 3) * 1024 + w * 8 + (c0 & 7)] = e;
  }
  __syncthreads();
#pragma unroll
  for (int i = 0; i < 4; ++i) {
    const int idx = i * 512 + threadIdx.x;   // 2048 x 16B, linear
    *(uint4*)(outp + idx * 8) = *(const uint4*)&pl[idx * 8];
  }
}

// ---- pass 2: banded Gram via MFMA. Block=(b,h); 8 waves = 8 m-tiles;
// per di: diag tile (n0=m0) + sub tile (n0=m0-16), K=128 as 4 chunks.
__global__ __launch_bounds__(512, 2) void costvol_kernel(const ushort* __restrict__ ws,
                                                         float* __restrict__ out) {
  __shared__ float outlds[ND * TILE];     // 41.5 KB: 9 di slices
  const int tid  = threadIdx.x;
  const int lane = tid & 63;
  const int wave = tid >> 6;              // m-tile
  const int col  = lane & 15;
  const int g    = lane >> 4;

  // XCD-pinned decode (grid 256): xcd owns (b, h-half); h-contiguous
  // blocks (sharing 8/9 tgt planes) stay on one XCD's L2.
  const int xcd = blockIdx.x & 7;
  const int b   = xcd >> 1;
  const int h   = ((xcd & 1) << 5) | (blockIdx.x >> 3);

  const ushort* ap = ws + (size_t)(b * NH + h) * PLANE;
  const ushort* tb = ws + TGT_OFF + (size_t)(b * NH) * PLANE;
  const int m0 = wave << 4;

  // A fragments: loaded ONCE for all 9 di (16 VGPR).
  short8 A[4];
#pragma unroll
  for (int kk = 0; kk < 4; ++kk)
    A[kk] = *(const short8*)&ap[(4 * kk + g) * 1024 + (m0 + col) * 8];

#pragma unroll
  for (int di = 0; di < ND; ++di) {
    const int y = h + di - 8;             // uniform per block
    if (y >= 0) {
      const ushort* tp = tb + (size_t)y * PLANE;
      short8 BD[4], BS[4];
#pragma unroll
      for (int kk = 0; kk < 4; ++kk) {
        const int off = (4 * kk + g) * 1024 + (m0 + col) * 8;
        BD[kk] = *(const short8*)&tp[off];
      }
      if (wave) {
#pragma unroll
        for (int kk = 0; kk < 4; ++kk)
          BS[kk] = *(const short8*)&tp[(4 * kk + g) * 1024 + (m0 - 16 + col) * 8];
      }

      f32x4 accD = {0.f, 0.f, 0.f, 0.f};
      f32x4 accS = {0.f, 0.f, 0.f, 0.f};
#pragma unroll
      for (int kk = 0; kk < 4; ++kk)
        accD = __builtin_amdgcn_mfma_f32_16x16x32_bf16(A[kk], BD[kk], accD, 0, 0, 0);
      if (wave) {
#pragma unroll
        for (int kk = 0; kk < 4; ++kk)
          accS = __builtin_amdgcn_mfma_f32_16x16x32_bf16(A[kk], BS[kk], accS, 0, 0, 0);
      }

      // band extraction (v7/v8-verified): C/D layout col=lane&15, row=4g+q.
      // diag: dj=col-row+8; sub: dj=col-row-8. Per-di slice + bank swizzle
      // ((w+4dj)&127). Slices are disjoint -> no barrier inside the loop.
      float* ol = &outlds[di * TILE];
#pragma unroll
      for (int q = 0; q < 4; ++q) {
        const int row = 4 * g + q;
        const int w   = m0 + row;
        const int djd = col - row + 8;
        if (djd >= 0 && djd <= 8)
          ol[djd * NW + ((w + 4 * djd) & 127)] = accD[q];
        if (wave) {
          const int djs = col - row - 8;
          if (djs >= 0 && djs <= 8)
            ol[djs * NW + ((w + 4 * djs) & 127)] = accS[q];
        }
      }
    }
  }

  __syncthreads();   // all scatters done (the ONLY barrier)

  // store pass: 81 (di,dj) rows x 128 w, coalesced float4. Zeros for the
  // w+dj<8 wedge and whole y<0 planes (stale LDS never leaks through).
  for (int s = tid; s < ND * ND * 32; s += 512) {
    const int di = s / (ND * 32);
    const int r  = s % (ND * 32);
    const int dj = r >> 5;
    const int w  = (r & 31) << 2;
    f32x4 o = *(const f32x4*)&outlds[di * TILE + dj * NW + ((w + 4 * dj) & 127)];
    const bool vb = (h + di - 8) >= 0;
#pragma unroll
    for (int i = 0; i < 4; ++i)
      if (!vb || (w + i + dj < 8)) o[i] = 0.f;
    *(f32x4*)(out + ((size_t)((b * NOUT + di * ND + dj) * NH + h)) * NW + w) = o;
  }
}

extern "C" void kernel_launch(void* const* d_in, const int* in_sizes, int n_in,
                              void* d_out, int out_size, void* d_ws, size_t ws_size,
                              hipStream_t stream) {
  const float* src = (const float*)d_in[0];
  const float* tgt = (const float*)d_in[1];
  float* out = (float*)d_out;
  ushort* ws = (ushort*)d_ws;
  convert_kernel<<<dim3(2 * NB * NH), dim3(512), 0, stream>>>(src, tgt, ws);
  costvol_kernel<<<dim3(NB * NH), dim3(512), 0, stream>>>(ws, out);
}